// Round 1
// baseline (390.024 us; speedup 1.0000x reference)
//
#include <hip/hip_runtime.h>
#include <stdint.h>

#define AS1 __attribute__((address_space(1)))
#define AS3 __attribute__((address_space(3)))

typedef unsigned short ushort_t;
typedef __attribute__((ext_vector_type(8))) short bf16x8;
typedef __attribute__((ext_vector_type(4))) float f32x4;

__device__ __forceinline__ ushort_t f2bf(float f) {
  union { float f; uint32_t u; } c; c.f = f;
  uint32_t u = c.u;
  return (ushort_t)((u + 0x7fffu + ((u >> 16) & 1u)) >> 16);  // RNE
}
__device__ __forceinline__ float bflo(uint32_t w) {
  union { uint32_t u; float f; } c; c.u = w << 16; return c.f;
}
__device__ __forceinline__ float bfhi(uint32_t w) {
  union { uint32_t u; float f; } c; c.u = w & 0xffff0000u; return c.f;
}

// ---------------- prep kernels ----------------

__global__ __launch_bounds__(256) void k_cvt4(const float* __restrict__ in,
                                              ushort_t* __restrict__ out, int n4) {
  int i = blockIdx.x * blockDim.x + threadIdx.x;
  int stride = gridDim.x * blockDim.x;
  for (; i < n4; i += stride) {
    float4 v = ((const float4*)in)[i];
    ushort4 o;
    o.x = f2bf(v.x); o.y = f2bf(v.y); o.z = f2bf(v.z); o.w = f2bf(v.w);
    ((ushort4*)out)[i] = o;
  }
}

__global__ __launch_bounds__(256) void k_suminit(const float* __restrict__ init,
                                                 float* __restrict__ s) {
  int i = blockIdx.x * 256 + threadIdx.x;
  if (i < 1024) s[i] = init[i] + init[i + 1024] + init[i + 2048];
}

// W [K][N] fp32 -> Wt [N][K] bf16
__global__ __launch_bounds__(256) void k_transpose(const float* __restrict__ W,
                                                   ushort_t* __restrict__ Wt,
                                                   int K, int N) {
  __shared__ float tile[32][33];
  int tx = threadIdx.x & 31, ty = threadIdx.x >> 5;  // 32 x 8
  int n0 = blockIdx.x * 32, k0 = blockIdx.y * 32;
  #pragma unroll
  for (int i = ty; i < 32; i += 8)
    tile[i][tx] = W[(size_t)(k0 + i) * N + (n0 + tx)];
  __syncthreads();
  #pragma unroll
  for (int i = ty; i < 32; i += 8)
    Wt[(size_t)(n0 + i) * K + (k0 + tx)] = f2bf(tile[tx][i]);
}

// ---------------- GEMM: C[M,1024] = A[M,KT] * Bt[1024,KT]^T  (bf16 in, fp32 acc) ----------------
// EPI 0: bf16(relu(acc+bias))
// EPI 1: bf16(3*relu(acc+bias) + extra[col])
// EPI 2: bf16(3*relu(acc+bias))

template <int KT, int EPI>
__global__ __launch_bounds__(256, 2)
void gemm_bt(const ushort_t* __restrict__ A, const ushort_t* __restrict__ Bt,
             const float* __restrict__ bias, const float* __restrict__ extra,
             ushort_t* __restrict__ C) {
  __shared__ char smem[32768];
  char* smA = smem;            // [128 rows][128 bytes] (BK=64 bf16), XOR-swizzled content
  char* smB = smem + 16384;    // same for Bt tile

  // XCD-aware swizzle: nwg = 2048, divisible by 8
  const int nwg = gridDim.x;
  const int cpx = nwg >> 3;
  int bid = blockIdx.x;
  int wg = (bid & 7) * cpx + (bid >> 3);
  const int mt = wg >> 3;  // 256 m-tiles
  const int nt = wg & 7;   // 8 n-tiles

  const int t = threadIdx.x;
  const int wave = t >> 6;
  const int lane = t & 63;
  const int wr = wave >> 1, wc = wave & 1;
  const int lrow = lane & 15;
  const int kq = lane >> 4;

  const char* Abase = (const char*)A + (size_t)mt * 128 * (KT * 2);
  const char* Bbase = (const char*)Bt + (size_t)nt * 128 * (KT * 2);

  // staging geometry: call i stages rows [i*32 .. i*32+31]; this thread's row within group:
  const int rbase = wave * 8 + (lane >> 3);
  // pre-swizzled global source column (16B units XORed with row parity)
  const int colOff = ((lane & 7) ^ (rbase & 7)) << 4;

  f32x4 acc[4][4];
  #pragma unroll
  for (int m = 0; m < 4; ++m)
    #pragma unroll
    for (int n = 0; n < 4; ++n)
      acc[m][n] = (f32x4){0.f, 0.f, 0.f, 0.f};

  constexpr int NKT = KT / 64;
  for (int kt = 0; kt < NKT; ++kt) {
    const size_t kb = (size_t)kt * 128;  // byte offset of K-tile in a row
    #pragma unroll
    for (int i = 0; i < 4; ++i) {
      int r = i * 32 + rbase;
      __builtin_amdgcn_global_load_lds(
          (const AS1 void*)(Abase + (size_t)r * (KT * 2) + kb + colOff),
          (AS3 void*)(smA + i * 4096 + wave * 1024), 16, 0, 0);
      __builtin_amdgcn_global_load_lds(
          (const AS1 void*)(Bbase + (size_t)r * (KT * 2) + kb + colOff),
          (AS3 void*)(smB + i * 4096 + wave * 1024), 16, 0, 0);
    }
    __syncthreads();
    #pragma unroll
    for (int ks = 0; ks < 2; ++ks) {
      bf16x8 af[4], bfv[4];
      #pragma unroll
      for (int m = 0; m < 4; ++m) {
        int r = wr * 64 + m * 16 + lrow;
        af[m] = *(const bf16x8*)(smA + r * 128 +
                                 ((ks * 64 + kq * 16) ^ ((r & 7) << 4)));
      }
      #pragma unroll
      for (int n = 0; n < 4; ++n) {
        int r = wc * 64 + n * 16 + lrow;
        bfv[n] = *(const bf16x8*)(smB + r * 128 +
                                  ((ks * 64 + kq * 16) ^ ((r & 7) << 4)));
      }
      #pragma unroll
      for (int m = 0; m < 4; ++m)
        #pragma unroll
        for (int n = 0; n < 4; ++n)
          acc[m][n] = __builtin_amdgcn_mfma_f32_16x16x32_bf16(af[m], bfv[n],
                                                              acc[m][n], 0, 0, 0);
    }
    __syncthreads();
  }

  // epilogue: C/D layout col = lane&15, row = (lane>>4)*4 + j
  const int row0 = mt * 128 + wr * 64;
  const int col0 = nt * 128 + wc * 64;
  #pragma unroll
  for (int n = 0; n < 4; ++n) {
    int col = col0 + n * 16 + lrow;
    float bn = bias[col];
    float en = 0.f;
    if (EPI == 1) en = extra[col];
    #pragma unroll
    for (int m = 0; m < 4; ++m) {
      int rb = row0 + m * 16 + kq * 4;
      #pragma unroll
      for (int j = 0; j < 4; ++j) {
        float v = acc[m][n][j] + bn;
        v = fmaxf(v, 0.f);
        if (EPI == 1) v = 3.f * v + en;
        else if (EPI == 2) v = 3.f * v;
        C[(size_t)(rb + j) * 1024 + col] = f2bf(v);
      }
    }
  }
}

// ---------------- decoder: out[b*3 + {0,1,2}] = dot(h2[b,:], dec_w) + dec_b ----------------

__global__ __launch_bounds__(256) void k_decode(const ushort_t* __restrict__ h2,
                                                const float* __restrict__ dw,
                                                const float* __restrict__ db,
                                                float* __restrict__ out) {
  int wave = threadIdx.x >> 6, lane = threadIdx.x & 63;
  int row = blockIdx.x * 4 + wave;
  const uint4* p = (const uint4*)(h2 + (size_t)row * 1024 + lane * 16);
  const float4* w = (const float4*)(dw + lane * 16);
  uint4 v0 = p[0], v1 = p[1];
  float4 w0 = w[0], w1 = w[1], w2 = w[2], w3 = w[3];
  float s = 0.f;
  s += bflo(v0.x) * w0.x + bfhi(v0.x) * w0.y;
  s += bflo(v0.y) * w0.z + bfhi(v0.y) * w0.w;
  s += bflo(v0.z) * w1.x + bfhi(v0.z) * w1.y;
  s += bflo(v0.w) * w1.z + bfhi(v0.w) * w1.w;
  s += bflo(v1.x) * w2.x + bfhi(v1.x) * w2.y;
  s += bflo(v1.y) * w2.z + bfhi(v1.y) * w2.w;
  s += bflo(v1.z) * w3.x + bfhi(v1.z) * w3.y;
  s += bflo(v1.w) * w3.z + bfhi(v1.w) * w3.w;
  #pragma unroll
  for (int off = 32; off; off >>= 1) s += __shfl_xor(s, off);
  if (lane == 0) {
    float r = s + db[0];
    out[row * 3 + 0] = r;
    out[row * 3 + 1] = r;
    out[row * 3 + 2] = r;
  }
}

// ---------------- launch ----------------

extern "C" void kernel_launch(void* const* d_in, const int* in_sizes, int n_in,
                              void* d_out, int out_size, void* d_ws, size_t ws_size,
                              hipStream_t stream) {
  const float* x      = (const float*)d_in[0];
  const float* enc_w1 = (const float*)d_in[1];
  const float* enc_b1 = (const float*)d_in[2];
  const float* enc_w2 = (const float*)d_in[3];
  const float* enc_b2 = (const float*)d_in[4];
  const float* initn  = (const float*)d_in[5];
  const float* g1w1   = (const float*)d_in[6];
  const float* g1b1   = (const float*)d_in[7];
  const float* g1w2   = (const float*)d_in[8];
  const float* g1b2   = (const float*)d_in[9];
  const float* g2w1   = (const float*)d_in[10];
  const float* g2b1   = (const float*)d_in[11];
  const float* g2w2   = (const float*)d_in[12];
  const float* g2b2   = (const float*)d_in[13];
  const float* dec_w  = (const float*)d_in[14];
  const float* dec_b  = (const float*)d_in[15];
  float* out = (float*)d_out;

  char* ws = (char*)d_ws;
  ushort_t* xb    = (ushort_t*)(ws + 0);          // 32768*512*2  = 33,554,432
  ushort_t* wtE1  = (ushort_t*)(ws + 33554432);   // 1024*512*2   =  1,048,576
  ushort_t* wtE2  = (ushort_t*)(ws + 34603008);   // 1024*1024*2  =  2,097,152
  ushort_t* wtG11 = (ushort_t*)(ws + 36700160);
  ushort_t* wtG12 = (ushort_t*)(ws + 38797312);
  ushort_t* wtG21 = (ushort_t*)(ws + 40894464);
  ushort_t* wtG22 = (ushort_t*)(ws + 42991616);
  float*    sInit = (float*)   (ws + 45088768);   // 4 KB
  ushort_t* bufA  = (ushort_t*)(ws + 45092864);   // 32768*1024*2 = 67,108,864
  ushort_t* bufB  = (ushort_t*)(ws + 112201728);  // 67,108,864  (end ≈ 179.3 MB)

  // prep
  k_cvt4<<<2048, 256, 0, stream>>>(x, xb, 32768 * 512 / 4);
  k_suminit<<<4, 256, 0, stream>>>(initn, sInit);
  {
    dim3 g512(32, 16), g1024(32, 32);
    k_transpose<<<g512, 256, 0, stream>>>(enc_w1, wtE1, 512, 1024);
    k_transpose<<<g1024, 256, 0, stream>>>(enc_w2, wtE2, 1024, 1024);
    k_transpose<<<g1024, 256, 0, stream>>>(g1w1, wtG11, 1024, 1024);
    k_transpose<<<g1024, 256, 0, stream>>>(g1w2, wtG12, 1024, 1024);
    k_transpose<<<g1024, 256, 0, stream>>>(g2w1, wtG21, 1024, 1024);
    k_transpose<<<g1024, 256, 0, stream>>>(g2w2, wtG22, 1024, 1024);
  }

  // e1 = relu(x @ enc_w1 + b1)
  gemm_bt<512, 0><<<2048, 256, 0, stream>>>(xb, wtE1, enc_b1, nullptr, bufA);
  // S1 = 3*relu(e1 @ enc_w2 + b2) + sum_init
  gemm_bt<1024, 1><<<2048, 256, 0, stream>>>(bufA, wtE2, enc_b2, sInit, bufB);
  // t1 = relu(S1 @ g1w1 + g1b1)
  gemm_bt<1024, 0><<<2048, 256, 0, stream>>>(bufB, wtG11, g1b1, nullptr, bufA);
  // m2 = 3*relu(t1 @ g1w2 + g1b2)
  gemm_bt<1024, 2><<<2048, 256, 0, stream>>>(bufA, wtG12, g1b2, nullptr, bufB);
  // t2 = relu(m2 @ g2w1 + g2b1)
  gemm_bt<1024, 0><<<2048, 256, 0, stream>>>(bufB, wtG21, g2b1, nullptr, bufA);
  // h2 = relu(t2 @ g2w2 + g2b2)
  gemm_bt<1024, 0><<<2048, 256, 0, stream>>>(bufA, wtG22, g2b2, nullptr, bufB);
  // out[b, 0..2] = dot(h2[b], dec_w) + dec_b
  k_decode<<<8192, 256, 0, stream>>>(bufB, dec_w, dec_b, out);
}